// Round 8
// baseline (556.053 us; speedup 1.0000x reference)
//
#include <hip/hip_runtime.h>

// Shapes (fixed): B=4, S=2048, D=2048, H=16, hd=128, F=3D=6144, M=B*S=8192
typedef float f32x4 __attribute__((ext_vector_type(4)));
typedef __bf16 bf16x8 __attribute__((ext_vector_type(8)));
typedef __bf16 bf16x4 __attribute__((ext_vector_type(4)));

#define EPSF 1e-6f
#define AS1 __attribute__((address_space(1)))
#define AS3 __attribute__((address_space(3)))

__device__ static inline void gl_lds16(const __bf16* g, __bf16* l) {
  // async global->LDS, 16B/lane, LDS dest = uniform base + lane*16
  __builtin_amdgcn_global_load_lds((const AS1 void*)g, (AS3 void*)l, 16, 0, 0);
}

__device__ static inline unsigned pack_bf16(float a, float b) {
  // low half = bf16(a), high half = bf16(b)
  union { __bf16 h; unsigned short u; } x, y;
  x.h = (__bf16)a; y.h = (__bf16)b;
  return ((unsigned)y.u << 16) | (unsigned)x.u;
}

// ---------------- weight unit-norm (rows) + bf16 cast ----------------
__global__ __launch_bounds__(256) void norm_w(const float* __restrict__ w_in,
                                              const float* __restrict__ w_out,
                                              __bf16* __restrict__ w_in_n,
                                              __bf16* __restrict__ w_out_n) {
  __shared__ float red[4];
  const int row = blockIdx.x;
  const float* src = (row < 6144) ? (w_in + (size_t)row * 2048)
                                  : (w_out + (size_t)(row - 6144) * 2048);
  __bf16* dst = (row < 6144) ? (w_in_n + (size_t)row * 2048)
                             : (w_out_n + (size_t)(row - 6144) * 2048);
  const int t = threadIdx.x;
  float4 v[2];
  float ss = 0.f;
#pragma unroll
  for (int i = 0; i < 2; i++) {
    v[i] = ((const float4*)src)[t + i * 256];
    ss += v[i].x * v[i].x + v[i].y * v[i].y + v[i].z * v[i].z + v[i].w * v[i].w;
  }
#pragma unroll
  for (int m = 32; m >= 1; m >>= 1) ss += __shfl_xor(ss, m);
  if ((t & 63) == 0) red[t >> 6] = ss;
  __syncthreads();
  float tot = red[0] + red[1] + red[2] + red[3];
  float sc = rsqrtf(tot + EPSF);  // unit_norm: SUM of squares
#pragma unroll
  for (int i = 0; i < 2; i++) {
    bf16x4 o;
    o[0] = (__bf16)(v[i].x * sc);
    o[1] = (__bf16)(v[i].y * sc);
    o[2] = (__bf16)(v[i].z * sc);
    o[3] = (__bf16)(v[i].w * sc);
    *(bf16x4*)(dst + (t + i * 256) * 4) = o;
  }
}

// ---------------- x f32 -> bf16 ----------------
__global__ __launch_bounds__(256) void cast_x(const float* __restrict__ x,
                                              __bf16* __restrict__ xb) {
  size_t i = ((size_t)blockIdx.x * 256 + threadIdx.x) * 8;
  float4 a = ((const float4*)(x + i))[0];
  float4 b = ((const float4*)(x + i))[1];
  bf16x8 o;
  o[0] = (__bf16)a.x; o[1] = (__bf16)a.y; o[2] = (__bf16)a.z; o[3] = (__bf16)a.w;
  o[4] = (__bf16)b.x; o[5] = (__bf16)b.y; o[6] = (__bf16)b.z; o[7] = (__bf16)b.w;
  *(bf16x8*)(xb + i) = o;
}

// ---------------- 256x256 3-phase GEMM  C = A[MxK] * W[NxK]^T, bf16 ----------------
// (structure unchanged from round 2.) MODE 1 v-epilogue now writes vt with
// columns PAIR-INTERLEAVED within each 32-chunk: position p of a chunk holds
// original k where p = 2*(k&15) + (k>>4&1). This makes P (k, k+16) pairs
// adjacent for attn's packed b32 P-transpose writes (pair order verified to
// match on the P A-operand and V B-operand sides).
#define LDSOFF(r_, blk_) ((r_) * 64 + (((blk_) ^ ((r_) & 7)) * 8))
#define SA(bb_, c_, kt_) gl_lds16(gA + (long)(c_) * 64 * K + (long)(kt_) * 64, &As[bb_][(c_) * 4096 + t * 8])
#define SB(bb_, c_, kt_) gl_lds16(gB + (long)(c_) * 64 * K + (long)(kt_) * 64, &Bs[bb_][(c_) * 4096 + t * 8])

template <int MODE>
__global__ __launch_bounds__(512) void gemm8(const __bf16* __restrict__ A,
                                             const __bf16* __restrict__ W,
                                             float* __restrict__ C,
                                             __bf16* __restrict__ Cb,
                                             __bf16* __restrict__ Vtb,
                                             int M, int N, int K) {
  __shared__ __bf16 As[2][16384];  // [buf][256 rows x 64 cols]
  __shared__ __bf16 Bs[2][16384];
  __shared__ float rsum[8][128];

  // XCD-aware bijective block swizzle (nwg % 8 == 0 for all launches)
  const int gx = gridDim.x;
  const int nwg = gx * gridDim.y;
  int wg = blockIdx.y * gx + blockIdx.x;
  wg = (wg & 7) * (nwg >> 3) + (wg >> 3);
  const int bx = wg % gx, by = wg / gx;

  const int t = threadIdx.x;
  const int lane = t & 63, w = t >> 6;
  const int wr = w >> 2, wc = w & 3;        // 2M x 4N wave grid
  const int wrb = wr * 128, wcb = wc * 64;  // wave tile origin in block
  const int fr = lane & 15, fq = lane >> 4;
  const long m0 = (long)by * 256;
  const long n0 = (long)bx * 256;
  const int NT = K >> 6;

  // staging source (pre-swizzled global column so linear LDS dest lands swizzled)
  const int srow = t >> 3;                       // 0..63 within a 64-row call
  const int sblk = (t & 7) ^ (srow & 7);
  const __bf16* gA = A + (m0 + srow) * (long)K + sblk * 8;
  const __bf16* gB = W + (n0 + srow) * (long)K + sblk * 8;

  f32x4 acc[8][4];
#pragma unroll
  for (int i = 0; i < 8; i++)
#pragma unroll
    for (int j = 0; j < 4; j++)
#pragma unroll
      for (int c = 0; c < 4; c++) acc[i][j][c] = 0.f;

  // ---- prologue: tile0 fully, tile1 {s0 A c0c2, s1s2 B all}; counted wait ----
  SA(0, 0, 0); SA(0, 1, 0); SA(0, 2, 0); SA(0, 3, 0);
  SB(0, 0, 0); SB(0, 1, 0); SB(0, 2, 0); SB(0, 3, 0);
  SA(1, 0, 1); SA(1, 2, 1);
  SB(1, 0, 1); SB(1, 1, 1); SB(1, 2, 1); SB(1, 3, 1);
  asm volatile("s_waitcnt vmcnt(6)" ::: "memory");  // tile0 complete, 3 half-tiles in flight
  __builtin_amdgcn_s_barrier();

  auto tile_step = [&](int kt, int b) {
    // -------- P0: read a0+b01; stage (kt+1)s3; MFMA left-half of top ----
    bf16x8 a0[4][2], b01[2][2];
#pragma unroll
    for (int i = 0; i < 4; i++)
#pragma unroll
      for (int ks = 0; ks < 2; ks++)
        a0[i][ks] = *(const bf16x8*)&As[b][LDSOFF(wrb + i * 16 + fr, ks * 4 + fq)];
#pragma unroll
    for (int j = 0; j < 2; j++)
#pragma unroll
      for (int ks = 0; ks < 2; ks++)
        b01[j][ks] = *(const bf16x8*)&Bs[b][LDSOFF(wcb + j * 16 + fr, ks * 4 + fq)];
    if (kt + 1 < NT) { SA(b ^ 1, 1, kt + 1); SA(b ^ 1, 3, kt + 1); }
    __builtin_amdgcn_s_setprio(1);
#pragma unroll
    for (int i = 0; i < 4; i++)
#pragma unroll
      for (int j = 0; j < 2; j++)
#pragma unroll
        for (int ks = 0; ks < 2; ks++)
          acc[i][j] = __builtin_amdgcn_mfma_f32_16x16x32_bf16(a0[i][ks], b01[j][ks], acc[i][j], 0, 0, 0);
    __builtin_amdgcn_s_setprio(0);
    __builtin_amdgcn_sched_barrier(0);
    __builtin_amdgcn_s_barrier();

    // -------- P1: read b23; stage (kt+2)s0; MFMA right-half of top ----
    bf16x8 b23[2][2];
#pragma unroll
    for (int j = 0; j < 2; j++)
#pragma unroll
      for (int ks = 0; ks < 2; ks++)
        b23[j][ks] = *(const bf16x8*)&Bs[b][LDSOFF(wcb + (2 + j) * 16 + fr, ks * 4 + fq)];
    if (kt + 2 < NT) { SA(b, 0, kt + 2); SA(b, 2, kt + 2); }
    __builtin_amdgcn_s_setprio(1);
#pragma unroll
    for (int i = 0; i < 4; i++)
#pragma unroll
      for (int j = 0; j < 2; j++)
#pragma unroll
        for (int ks = 0; ks < 2; ks++)
          acc[i][2 + j] = __builtin_amdgcn_mfma_f32_16x16x32_bf16(a0[i][ks], b23[j][ks], acc[i][2 + j], 0, 0, 0);
    __builtin_amdgcn_s_setprio(0);
    __builtin_amdgcn_sched_barrier(0);
    __builtin_amdgcn_s_barrier();

    // -------- P2: read a1; stage (kt+2)s1,s2; MFMA bottom half; boundary vmcnt ----
    bf16x8 a1[4][2];
#pragma unroll
    for (int i = 0; i < 4; i++)
#pragma unroll
      for (int ks = 0; ks < 2; ks++)
        a1[i][ks] = *(const bf16x8*)&As[b][LDSOFF(wrb + 64 + i * 16 + fr, ks * 4 + fq)];
    if (kt + 2 < NT) { SB(b, 0, kt + 2); SB(b, 1, kt + 2); SB(b, 2, kt + 2); SB(b, 3, kt + 2); }
    __builtin_amdgcn_s_setprio(1);
#pragma unroll
    for (int i = 0; i < 4; i++)
#pragma unroll
      for (int j = 0; j < 2; j++)
#pragma unroll
        for (int ks = 0; ks < 2; ks++)
          acc[4 + i][j] = __builtin_amdgcn_mfma_f32_16x16x32_bf16(a1[i][ks], b01[j][ks], acc[4 + i][j], 0, 0, 0);
#pragma unroll
    for (int i = 0; i < 4; i++)
#pragma unroll
      for (int j = 0; j < 2; j++)
#pragma unroll
        for (int ks = 0; ks < 2; ks++)
          acc[4 + i][2 + j] = __builtin_amdgcn_mfma_f32_16x16x32_bf16(a1[i][ks], b23[j][ks], acc[4 + i][2 + j], 0, 0, 0);
    __builtin_amdgcn_s_setprio(0);
    if (kt >= NT - 2)
      asm volatile("s_waitcnt vmcnt(0)" ::: "memory");  // epilogue drain
    else
      asm volatile("s_waitcnt vmcnt(6)" ::: "memory");  // tile kt+1 fully staged
    __builtin_amdgcn_sched_barrier(0);
    __builtin_amdgcn_s_barrier();
  };

  for (int kt = 0; kt < NT; kt += 2) {
    tile_step(kt, 0);
    tile_step(kt + 1, 1);
  }

  // ---------------- epilogue ----------------
  if (MODE == 0) {
#pragma unroll
    for (int i = 0; i < 8; i++)
#pragma unroll
      for (int j = 0; j < 4; j++)
#pragma unroll
        for (int r = 0; r < 4; r++) {
          long row = m0 + wrb + i * 16 + fq * 4 + r;  // C/D: row=(lane>>4)*4+reg
          long col = n0 + wcb + j * 16 + fr;          // C/D: col=lane&15
          C[row * N + col] = acc[i][j][r];
        }
  } else {
    const int tt = (int)(n0 >> 11);                         // 0=q,1=k,2=v (block-uniform)
    const int hh = (int)(((n0 >> 7) + (wc >> 1)) & 15);     // head (wave-uniform)
    const long e0 = (long)(wc & 1) * 64;                    // e offset of wave's 64 cols
    if (tt < 2) {
      // rms-norm over e (=128): partner wave w^1 holds the other 64 cols of the head
#pragma unroll
      for (int i = 0; i < 8; i++)
#pragma unroll
        for (int r = 0; r < 4; r++) {
          float s2 = 0.f;
#pragma unroll
          for (int j = 0; j < 4; j++) s2 += acc[i][j][r] * acc[i][j][r];
          s2 += __shfl_xor(s2, 1);
          s2 += __shfl_xor(s2, 2);
          s2 += __shfl_xor(s2, 4);
          s2 += __shfl_xor(s2, 8);
          if (fr == 0) rsum[w][i * 16 + fq * 4 + r] = s2;
        }
      __syncthreads();
#pragma unroll
      for (int i = 0; i < 8; i++)
#pragma unroll
        for (int r = 0; r < 4; r++) {
          int rl = i * 16 + fq * 4 + r;
          float tot = rsum[w][rl] + rsum[w ^ 1][rl];
          float sc = rsqrtf(tot * (1.f / 128.f) + EPSF);
          long row = m0 + wrb + rl;
          long bb = row >> 11, ss = row & 2047;
          __bf16* base = Cb + ((((long)tt * 4 + bb) * 16 + hh) * 2048 + ss) * 128 + e0;
#pragma unroll
          for (int j = 0; j < 4; j++)
            base[j * 16 + fr] = (__bf16)(acc[i][j][r] * sc);
        }
    } else {
#pragma unroll
      for (int i = 0; i < 8; i++)
#pragma unroll
        for (int r = 0; r < 4; r++) {
          long row = m0 + wrb + i * 16 + fq * 4 + r;
          long bb = row >> 11, ss = row & 2047;
          // pair-interleave within each 32-chunk: p = 2*(k&15) + (k>>4&1)
          long ssp = (ss & ~31L) | ((ss & 15) << 1) | ((ss >> 4) & 1);
#pragma unroll
          for (int j = 0; j < 4; j++)
            Vtb[((bb * 16 + hh) * 128 + e0 + j * 16 + fr) * 2048 + ssp] = (__bf16)acc[i][j][r];
        }
    }
  }
}

// ---------------- flash attention v9: v6 + packed b32 P-transpose writes ----
// grid = 512 blocks; qt = L>>6 (0..7), bh = (L&7)+8*((L>>3)&7).
// Block covers 128-row q-macro-tile qi (wave w owns rows qi*128+w*32..+31 as TWO
// 16-row fragments sharing every K/V LDS read) and its causal mirror 15-qi ->
// uniform 34 stages/block. K/V staged per stage via global_load_lds (single
// buffer, 42KB LDS -> 3 blocks/CU; inter-block TLP hides stage latency).
// P-transpose: vt columns are pair-interleaved (see gemm8 MODE1), so (p0,p1)
// for (k, k+16) pack into ONE ds_write_b32 at pair position fr — halves the
// P-write instruction count on the QK->PV critical path.
__global__ __launch_bounds__(256, 3) void attn(const __bf16* __restrict__ qkv,
                                               const __bf16* __restrict__ vt,
                                               __bf16* __restrict__ an) {
  __shared__ __bf16 Ks[64 * 128];   // [k row][128 e], 16B-blocks XOR-swizzled by (row&7)
  __shared__ __bf16 Vs[128 * 64];   // [e row][64 s], 16B-blocks XOR-swizzled by (row&7)
  __shared__ __bf16 plds[8][16 * 40];  // [w*2+f], row stride 40 bf16 = 20 u32
  const int L = blockIdx.x;
  const int qt = L >> 6;                        // 0..7
  const int bh = (L & 7) + 8 * ((L >> 3) & 7);  // 0..63
  const int t = threadIdx.x;
  const int lane = t & 63, w = t >> 6;          // w = 0..3
  const int fr = lane & 15, fq = lane >> 4;
  const int swz = fr & 7;
  const __bf16* Q = qkv + (long)bh * 262144;
  const __bf16* Kbh = qkv + 16777216L + (long)bh * 262144;
  const __bf16* Vbh = vt + (long)bh * 262144;
  const float sc2 = 0.08838834764831845f * 1.4426950408889634f;  // 1/sqrt(128)*log2(e)
  const float MFIX = 20.0f;  // |score*log2e/sqrt(hd)| <= 16.34 after rms-norm
  const int b = bh >> 4, h = bh & 15;

  // staging (256 threads, 4 calls each for K and V):
  const __bf16* gK = Kbh + (long)(t >> 4) * 128 + ((t & 15) ^ ((t >> 4) & 7)) * 8;
  const __bf16* gV = Vbh + (long)(t >> 3) * 2048 + ((t & 7) ^ ((t >> 3) & 7)) * 8;
  __bf16* lK = &Ks[t * 8];
  __bf16* lV = &Vs[t * 8];

#pragma unroll 1
  for (int side = 0; side < 2; side++) {
    const int qi = side ? (15 - qt) : qt;  // macro-tile 0..15
    const int q0 = qi * 128 + w * 32;      // this wave's 32 q rows (32-aligned)
    const int cha = q0 >> 5;               // diagonal 32-chunk (covers all 32 rows)
    bf16x8 qf[2][4];
#pragma unroll
    for (int f = 0; f < 2; f++)
#pragma unroll
      for (int ec = 0; ec < 4; ec++)
        qf[f][ec] = *(const bf16x8*)(Q + (long)(q0 + f * 16 + fr) * 128 + ec * 32 + fq * 8);
    float lacc[2][4];
#pragma unroll
    for (int f = 0; f < 2; f++)
#pragma unroll
      for (int r = 0; r < 4; r++) lacc[f][r] = 0.f;
    f32x4 oacc[2][8];
#pragma unroll
    for (int f = 0; f < 2; f++)
#pragma unroll
      for (int e = 0; e < 8; e++)
#pragma unroll
        for (int c = 0; c < 4; c++) oacc[f][e][c] = 0.f;

    const int nst = 2 * qi + 2;
#pragma unroll 1
    for (int st = 0; st < nst; st++) {
      const long k0 = (long)st * 64;
#pragma unroll
      for (int j = 0; j < 4; j++) gl_lds16(gK + (k0 + j * 16) * 128, lK + j * 2048);
#pragma unroll
      for (int j = 0; j < 4; j++) gl_lds16(gV + (long)j * 32 * 2048 + k0, lV + j * 2048);
      __syncthreads();
#pragma unroll
      for (int half = 0; half < 2; half++) {
        const int k32 = (int)k0 + half * 32;
        const int ch = k32 >> 5;
        if (ch <= cha) {  // wave-uniform causal skip
          f32x4 sa[2][2];
#pragma unroll
          for (int f = 0; f < 2; f++)
#pragma unroll
            for (int ct = 0; ct < 2; ct++)
#pragma unroll
              for (int c = 0; c < 4; c++) sa[f][ct][c] = 0.f;
          __builtin_amdgcn_s_setprio(1);
#pragma unroll
          for (int ct = 0; ct < 2; ct++) {
#pragma unroll
            for (int ec = 0; ec < 4; ec++) {
              bf16x8 kf = *(const bf16x8*)(&Ks[(half * 32 + ct * 16 + fr) * 128 +
                                               ((ec * 4 + fq) ^ swz) * 8]);
              sa[0][ct] = __builtin_amdgcn_mfma_f32_16x16x32_bf16(qf[0][ec], kf, sa[0][ct], 0, 0, 0);
              sa[1][ct] = __builtin_amdgcn_mfma_f32_16x16x32_bf16(qf[1][ec], kf, sa[1][ct], 0, 0, 0);
            }
          }
          __builtin_amdgcn_s_setprio(0);
#pragma unroll
          for (int f = 0; f < 2; f++) {
            unsigned* pwf32 = (unsigned*)plds[(w << 1) + f];
            if (ch == cha) {  // diagonal: masked
#pragma unroll
              for (int r = 0; r < 4; r++) {
                int qg = q0 + f * 16 + fq * 4 + r;
                float p0 = exp2f(((k32 + fr) <= qg) ? sa[f][0][r] * sc2 - MFIX : -1e30f);
                float p1 = exp2f(((k32 + 16 + fr) <= qg) ? sa[f][1][r] * sc2 - MFIX : -1e30f);
                lacc[f][r] += p0 + p1;
                pwf32[(fq * 4 + r) * 20 + fr] = pack_bf16(p0, p1);
              }
            } else {  // compare-free fast path
#pragma unroll
              for (int r = 0; r < 4; r++) {
                float p0 = exp2f(__builtin_fmaf(sa[f][0][r], sc2, -MFIX));
                float p1 = exp2f(__builtin_fmaf(sa[f][1][r], sc2, -MFIX));
                lacc[f][r] += p0 + p1;
                pwf32[(fq * 4 + r) * 20 + fr] = pack_bf16(p0, p1);
              }
            }
          }
          // P: C-layout -> LDS -> A-layout (wave-synchronous). Pair-interleaved
          // k-order on BOTH pa (pairs at 2fr,2fr+1) and vf (vt pre-permuted).
          bf16x8 pa0 = *(const bf16x8*)(&plds[(w << 1) + 0][fr * 40 + fq * 8]);
          bf16x8 pa1 = *(const bf16x8*)(&plds[(w << 1) + 1][fr * 40 + fq * 8]);
          __builtin_amdgcn_s_setprio(1);
#pragma unroll
          for (int e = 0; e < 8; e++) {
            bf16x8 vf = *(const bf16x8*)(&Vs[(e * 16 + fr) * 64 +
                                             ((half * 4 + fq) ^ swz) * 8]);
            oacc[0][e] = __builtin_amdgcn_mfma_f32_16x16x32_bf16(pa0, vf, oacc[0][e], 0, 0, 0);
            oacc[1][e] = __builtin_amdgcn_mfma_f32_16x16x32_bf16(pa1, vf, oacc[1][e], 0, 0, 0);
          }
          __builtin_amdgcn_s_setprio(0);
        }
      }
      __syncthreads();
    }
    // epilogue: reduce l; /l + rms-norm + store
#pragma unroll
    for (int f = 0; f < 2; f++)
#pragma unroll
      for (int r = 0; r < 4; r++) {
        float ls = lacc[f][r];
        ls += __shfl_xor(ls, 1);
        ls += __shfl_xor(ls, 2);
        ls += __shfl_xor(ls, 4);
        ls += __shfl_xor(ls, 8);
        float inv = 1.0f / ls;
        float ssq = 0.f;
#pragma unroll
        for (int e = 0; e < 8; e++) { float v = oacc[f][e][r] * inv; ssq += v * v; }
        ssq += __shfl_xor(ssq, 1);
        ssq += __shfl_xor(ssq, 2);
        ssq += __shfl_xor(ssq, 4);
        ssq += __shfl_xor(ssq, 8);
        float rsc = rsqrtf(ssq * (1.f / 128.f) + EPSF) * inv;
        long s = q0 + f * 16 + fq * 4 + r;
        __bf16* dst = an + ((long)b * 2048 + s) * 2048 + h * 128;
#pragma unroll
        for (int e = 0; e < 8; e++) dst[e * 16 + fr] = (__bf16)(oacc[f][e][r] * rsc);
      }
  }
}

// ---------------- launch ----------------
extern "C" void kernel_launch(void* const* d_in, const int* in_sizes, int n_in,
                              void* d_out, int out_size, void* d_ws, size_t ws_size,
                              hipStream_t stream) {
  const float* x = (const float*)d_in[0];
  const float* w_in = (const float*)d_in[1];
  const float* w_out = (const float*)d_in[2];
  float* out = (float*)d_out;
  char* ws = (char*)d_ws;

  __bf16* w_in_n = (__bf16*)(ws);                      // 25165824 B
  __bf16* w_out_n = (__bf16*)(ws + 25165824);          // 8388608 B
  __bf16* xb = (__bf16*)(ws + 33554432);               // 33554432 B (aliased by a_n)
  __bf16* an = xb;
  __bf16* qkv = (__bf16*)(ws + 67108864);              // q,k used (v region unused)
  __bf16* vt = (__bf16*)(ws + 167772160);              // 33554432 B

  norm_w<<<8192, 256, 0, stream>>>(w_in, w_out, w_in_n, w_out_n);
  cast_x<<<8192, 256, 0, stream>>>(x, xb);
  gemm8<1><<<dim3(24, 32), 512, 0, stream>>>(xb, w_in_n, nullptr, qkv, vt, 8192, 6144, 2048);
  attn<<<512, 256, 0, stream>>>(qkv, vt, an);
  gemm8<0><<<dim3(8, 32), 512, 0, stream>>>(an, w_out_n, out, nullptr, nullptr, 8192, 2048, 2048);
}

// Round 10
// 497.470 us; speedup vs baseline: 1.1178x; 1.1178x over previous
//
#include <hip/hip_runtime.h>

// Shapes (fixed): B=4, S=2048, D=2048, H=16, hd=128, F=3D=6144, M=B*S=8192
typedef float f32x4 __attribute__((ext_vector_type(4)));
typedef __bf16 bf16x8 __attribute__((ext_vector_type(8)));
typedef __bf16 bf16x4 __attribute__((ext_vector_type(4)));

#define EPSF 1e-6f
#define AS1 __attribute__((address_space(1)))
#define AS3 __attribute__((address_space(3)))

__device__ static inline void gl_lds16(const __bf16* g, __bf16* l) {
  // async global->LDS, 16B/lane, LDS dest = uniform base + lane*16
  __builtin_amdgcn_global_load_lds((const AS1 void*)g, (AS3 void*)l, 16, 0, 0);
}

// ---------------- weight unit-norm (rows) + bf16 cast ----------------
__global__ __launch_bounds__(256) void norm_w(const float* __restrict__ w_in,
                                              const float* __restrict__ w_out,
                                              __bf16* __restrict__ w_in_n,
                                              __bf16* __restrict__ w_out_n) {
  __shared__ float red[4];
  const int row = blockIdx.x;
  const float* src = (row < 6144) ? (w_in + (size_t)row * 2048)
                                  : (w_out + (size_t)(row - 6144) * 2048);
  __bf16* dst = (row < 6144) ? (w_in_n + (size_t)row * 2048)
                             : (w_out_n + (size_t)(row - 6144) * 2048);
  const int t = threadIdx.x;
  float4 v[2];
  float ss = 0.f;
#pragma unroll
  for (int i = 0; i < 2; i++) {
    v[i] = ((const float4*)src)[t + i * 256];
    ss += v[i].x * v[i].x + v[i].y * v[i].y + v[i].z * v[i].z + v[i].w * v[i].w;
  }
#pragma unroll
  for (int m = 32; m >= 1; m >>= 1) ss += __shfl_xor(ss, m);
  if ((t & 63) == 0) red[t >> 6] = ss;
  __syncthreads();
  float tot = red[0] + red[1] + red[2] + red[3];
  float sc = rsqrtf(tot + EPSF);  // unit_norm: SUM of squares
#pragma unroll
  for (int i = 0; i < 2; i++) {
    bf16x4 o;
    o[0] = (__bf16)(v[i].x * sc);
    o[1] = (__bf16)(v[i].y * sc);
    o[2] = (__bf16)(v[i].z * sc);
    o[3] = (__bf16)(v[i].w * sc);
    *(bf16x4*)(dst + (t + i * 256) * 4) = o;
  }
}

// ---------------- x f32 -> bf16 ----------------
__global__ __launch_bounds__(256) void cast_x(const float* __restrict__ x,
                                              __bf16* __restrict__ xb) {
  size_t i = ((size_t)blockIdx.x * 256 + threadIdx.x) * 8;
  float4 a = ((const float4*)(x + i))[0];
  float4 b = ((const float4*)(x + i))[1];
  bf16x8 o;
  o[0] = (__bf16)a.x; o[1] = (__bf16)a.y; o[2] = (__bf16)a.z; o[3] = (__bf16)a.w;
  o[4] = (__bf16)b.x; o[5] = (__bf16)b.y; o[6] = (__bf16)b.z; o[7] = (__bf16)b.w;
  *(bf16x8*)(xb + i) = o;
}

// ---------------- 256x256 3-phase GEMM  C = A[MxK] * W[NxK]^T, bf16 ----------------
// (structure = round 2.) A-resident block->XCD mapping: XCD x (= i0%8 dispatch
// round-robin) owns by in {4x..4x+3}: A row-panels (1-4MB) stay L2-resident per
// XCD and are reused across all gx column-blocks; B panels are streamed but
// shared across all 8 XCDs nearly in lockstep (L3-hot). Replaces the old mapping
// that streamed ALL of A per XCD (measured 320MB FETCH ~= 8x A + B).
#define LDSOFF(r_, blk_) ((r_) * 64 + (((blk_) ^ ((r_) & 7)) * 8))
#define SA(bb_, c_, kt_) gl_lds16(gA + (long)(c_) * 64 * K + (long)(kt_) * 64, &As[bb_][(c_) * 4096 + t * 8])
#define SB(bb_, c_, kt_) gl_lds16(gB + (long)(c_) * 64 * K + (long)(kt_) * 64, &Bs[bb_][(c_) * 4096 + t * 8])

template <int MODE>
__global__ __launch_bounds__(512) void gemm8(const __bf16* __restrict__ A,
                                             const __bf16* __restrict__ W,
                                             float* __restrict__ C,
                                             __bf16* __restrict__ Cb,
                                             __bf16* __restrict__ Vtb,
                                             int M, int N, int K) {
  __shared__ __bf16 As[2][16384];  // [buf][256 rows x 64 cols]
  __shared__ __bf16 Bs[2][16384];
  __shared__ float rsum[8][128];

  // A-resident XCD mapping (gridDim.y == 32, nwg % 8 == 0):
  // i -> XCD x = i%8, j = i/8; bx = j%gx, by = 4x + j/gx   (bijective: j/gx in 0..3)
  const int gx = gridDim.x;
  const int i0 = blockIdx.y * gx + blockIdx.x;
  const int xcd = i0 & 7;
  const int j0 = i0 >> 3;
  const int bx = j0 % gx;
  const int by = xcd * 4 + j0 / gx;

  const int t = threadIdx.x;
  const int lane = t & 63, w = t >> 6;
  const int wr = w >> 2, wc = w & 3;        // 2M x 4N wave grid
  const int wrb = wr * 128, wcb = wc * 64;  // wave tile origin in block
  const int fr = lane & 15, fq = lane >> 4;
  const long m0 = (long)by * 256;
  const long n0 = (long)bx * 256;
  const int NT = K >> 6;

  // staging source (pre-swizzled global column so linear LDS dest lands swizzled)
  const int srow = t >> 3;                       // 0..63 within a 64-row call
  const int sblk = (t & 7) ^ (srow & 7);
  const __bf16* gA = A + (m0 + srow) * (long)K + sblk * 8;
  const __bf16* gB = W + (n0 + srow) * (long)K + sblk * 8;

  f32x4 acc[8][4];
#pragma unroll
  for (int i = 0; i < 8; i++)
#pragma unroll
    for (int j = 0; j < 4; j++)
#pragma unroll
      for (int c = 0; c < 4; c++) acc[i][j][c] = 0.f;

  // ---- prologue: tile0 fully, tile1 {s0 A c0c2, s1s2 B all}; counted wait ----
  SA(0, 0, 0); SA(0, 1, 0); SA(0, 2, 0); SA(0, 3, 0);
  SB(0, 0, 0); SB(0, 1, 0); SB(0, 2, 0); SB(0, 3, 0);
  SA(1, 0, 1); SA(1, 2, 1);
  SB(1, 0, 1); SB(1, 1, 1); SB(1, 2, 1); SB(1, 3, 1);
  asm volatile("s_waitcnt vmcnt(6)" ::: "memory");  // tile0 complete, 3 half-tiles in flight
  __builtin_amdgcn_s_barrier();

  auto tile_step = [&](int kt, int b) {
    // -------- P0: read a0+b01; stage (kt+1)s3; MFMA left-half of top ----
    bf16x8 a0[4][2], b01[2][2];
#pragma unroll
    for (int i = 0; i < 4; i++)
#pragma unroll
      for (int ks = 0; ks < 2; ks++)
        a0[i][ks] = *(const bf16x8*)&As[b][LDSOFF(wrb + i * 16 + fr, ks * 4 + fq)];
#pragma unroll
    for (int j = 0; j < 2; j++)
#pragma unroll
      for (int ks = 0; ks < 2; ks++)
        b01[j][ks] = *(const bf16x8*)&Bs[b][LDSOFF(wcb + j * 16 + fr, ks * 4 + fq)];
    if (kt + 1 < NT) { SA(b ^ 1, 1, kt + 1); SA(b ^ 1, 3, kt + 1); }
    __builtin_amdgcn_s_setprio(1);
#pragma unroll
    for (int i = 0; i < 4; i++)
#pragma unroll
      for (int j = 0; j < 2; j++)
#pragma unroll
        for (int ks = 0; ks < 2; ks++)
          acc[i][j] = __builtin_amdgcn_mfma_f32_16x16x32_bf16(a0[i][ks], b01[j][ks], acc[i][j], 0, 0, 0);
    __builtin_amdgcn_s_setprio(0);
    __builtin_amdgcn_sched_barrier(0);
    __builtin_amdgcn_s_barrier();

    // -------- P1: read b23; stage (kt+2)s0; MFMA right-half of top ----
    bf16x8 b23[2][2];
#pragma unroll
    for (int j = 0; j < 2; j++)
#pragma unroll
      for (int ks = 0; ks < 2; ks++)
        b23[j][ks] = *(const bf16x8*)&Bs[b][LDSOFF(wcb + (2 + j) * 16 + fr, ks * 4 + fq)];
    if (kt + 2 < NT) { SA(b, 0, kt + 2); SA(b, 2, kt + 2); }
    __builtin_amdgcn_s_setprio(1);
#pragma unroll
    for (int i = 0; i < 4; i++)
#pragma unroll
      for (int j = 0; j < 2; j++)
#pragma unroll
        for (int ks = 0; ks < 2; ks++)
          acc[i][2 + j] = __builtin_amdgcn_mfma_f32_16x16x32_bf16(a0[i][ks], b23[j][ks], acc[i][2 + j], 0, 0, 0);
    __builtin_amdgcn_s_setprio(0);
    __builtin_amdgcn_sched_barrier(0);
    __builtin_amdgcn_s_barrier();

    // -------- P2: read a1; stage (kt+2)s1,s2; MFMA bottom half; boundary vmcnt ----
    bf16x8 a1[4][2];
#pragma unroll
    for (int i = 0; i < 4; i++)
#pragma unroll
      for (int ks = 0; ks < 2; ks++)
        a1[i][ks] = *(const bf16x8*)&As[b][LDSOFF(wrb + 64 + i * 16 + fr, ks * 4 + fq)];
    if (kt + 2 < NT) { SB(b, 0, kt + 2); SB(b, 1, kt + 2); SB(b, 2, kt + 2); SB(b, 3, kt + 2); }
    __builtin_amdgcn_s_setprio(1);
#pragma unroll
    for (int i = 0; i < 4; i++)
#pragma unroll
      for (int j = 0; j < 2; j++)
#pragma unroll
        for (int ks = 0; ks < 2; ks++)
          acc[4 + i][j] = __builtin_amdgcn_mfma_f32_16x16x32_bf16(a1[i][ks], b01[j][ks], acc[4 + i][j], 0, 0, 0);
#pragma unroll
    for (int i = 0; i < 4; i++)
#pragma unroll
      for (int j = 0; j < 2; j++)
#pragma unroll
        for (int ks = 0; ks < 2; ks++)
          acc[4 + i][2 + j] = __builtin_amdgcn_mfma_f32_16x16x32_bf16(a1[i][ks], b23[j][ks], acc[4 + i][2 + j], 0, 0, 0);
    __builtin_amdgcn_s_setprio(0);
    if (kt >= NT - 2)
      asm volatile("s_waitcnt vmcnt(0)" ::: "memory");  // epilogue drain
    else
      asm volatile("s_waitcnt vmcnt(6)" ::: "memory");  // tile kt+1 fully staged
    __builtin_amdgcn_sched_barrier(0);
    __builtin_amdgcn_s_barrier();
  };

  for (int kt = 0; kt < NT; kt += 2) {
    tile_step(kt, 0);
    tile_step(kt + 1, 1);
  }

  // ---------------- epilogue ----------------
  if (MODE == 0) {
#pragma unroll
    for (int i = 0; i < 8; i++)
#pragma unroll
      for (int j = 0; j < 4; j++)
#pragma unroll
        for (int r = 0; r < 4; r++) {
          long row = m0 + wrb + i * 16 + fq * 4 + r;  // C/D: row=(lane>>4)*4+reg
          long col = n0 + wcb + j * 16 + fr;          // C/D: col=lane&15
          C[row * N + col] = acc[i][j][r];
        }
  } else {
    const int tt = (int)(n0 >> 11);                         // 0=q,1=k,2=v (block-uniform)
    const int hh = (int)(((n0 >> 7) + (wc >> 1)) & 15);     // head (wave-uniform)
    const long e0 = (long)(wc & 1) * 64;                    // e offset of wave's 64 cols
    if (tt < 2) {
      // rms-norm over e (=128): partner wave w^1 holds the other 64 cols of the head
#pragma unroll
      for (int i = 0; i < 8; i++)
#pragma unroll
        for (int r = 0; r < 4; r++) {
          float s2 = 0.f;
#pragma unroll
          for (int j = 0; j < 4; j++) s2 += acc[i][j][r] * acc[i][j][r];
          s2 += __shfl_xor(s2, 1);
          s2 += __shfl_xor(s2, 2);
          s2 += __shfl_xor(s2, 4);
          s2 += __shfl_xor(s2, 8);
          if (fr == 0) rsum[w][i * 16 + fq * 4 + r] = s2;
        }
      __syncthreads();
#pragma unroll
      for (int i = 0; i < 8; i++)
#pragma unroll
        for (int r = 0; r < 4; r++) {
          int rl = i * 16 + fq * 4 + r;
          float tot = rsum[w][rl] + rsum[w ^ 1][rl];
          float sc = rsqrtf(tot * (1.f / 128.f) + EPSF);
          long row = m0 + wrb + rl;
          long bb = row >> 11, ss = row & 2047;
          __bf16* base = Cb + ((((long)tt * 4 + bb) * 16 + hh) * 2048 + ss) * 128 + e0;
#pragma unroll
          for (int j = 0; j < 4; j++)
            base[j * 16 + fr] = (__bf16)(acc[i][j][r] * sc);
        }
    } else {
#pragma unroll
      for (int i = 0; i < 8; i++)
#pragma unroll
        for (int r = 0; r < 4; r++) {
          long row = m0 + wrb + i * 16 + fq * 4 + r;
          long bb = row >> 11, ss = row & 2047;
#pragma unroll
          for (int j = 0; j < 4; j++)
            Vtb[((bb * 16 + hh) * 128 + e0 + j * 16 + fr) * 2048 + ss] = (__bf16)acc[i][j][r];
        }
    }
  }
}

// ---------------- flash attention v4 (round-1/2 measured-best) ----------------
// grid = 512 blocks; qt = L>>6 (0..7), bh = (L&7)+8*((L>>3)&7).
// Block covers 128-row q-macro-tile qi (wave w owns rows qi*128+w*16..+15) and its
// causal mirror 15-qi, sequentially -> uniform 34 stages/block. K/V (64x128 / 128x64)
// staged once per stage via global_load_lds, shared by all 8 waves. 16 waves/CU.
__global__ __launch_bounds__(512) void attn(const __bf16* __restrict__ qkv,
                                            const __bf16* __restrict__ vt,
                                            __bf16* __restrict__ an) {
  __shared__ __bf16 Ks[64 * 128];   // [k row][128 e], 16B-blocks XOR-swizzled by (row&7)
  __shared__ __bf16 Vs[128 * 64];   // [e row][64 s], 16B-blocks XOR-swizzled by (row&7)
  __shared__ __bf16 plds[8][16 * 40];
  const int L = blockIdx.x;
  const int qt = L >> 6;                        // 0..7
  const int bh = (L & 7) + 8 * ((L >> 3) & 7);  // 0..63
  const int t = threadIdx.x;
  const int lane = t & 63, w = t >> 6;          // w = 0..7
  const int fr = lane & 15, fq = lane >> 4;
  const int swz = fr & 7;
  const __bf16* Q = qkv + (long)bh * 262144;
  const __bf16* Kbh = qkv + 16777216L + (long)bh * 262144;
  const __bf16* Vbh = vt + (long)bh * 262144;
  __bf16* pw = plds[w];
  const float sc2 = 0.08838834764831845f * 1.4426950408889634f;  // 1/sqrt(128)*log2(e)
  const float MFIX = 20.0f;  // |score*log2e/sqrt(hd)| <= 16.34 after rms-norm
  const int b = bh >> 4, h = bh & 15;

  // staging (512 threads, 2 calls each for K and V):
  // K call j: slot s=j*512+t -> row s>>4, 16B-blk (s&15)^((s>>4)&7); dest Ks[s*8]
  const __bf16* gK = Kbh + (long)(t >> 4) * 128 + ((t & 15) ^ ((t >> 4) & 7)) * 8;
  // V call j: slot s=j*512+t -> row s>>3, blk (s&7)^((s>>3)&7); dest Vs[s*8]
  const __bf16* gV = Vbh + (long)(t >> 3) * 2048 + ((t & 7) ^ ((t >> 3) & 7)) * 8;
  __bf16* lK = &Ks[t * 8];
  __bf16* lV = &Vs[t * 8];

#pragma unroll 1
  for (int side = 0; side < 2; side++) {
    const int qi = side ? (15 - qt) : qt;  // macro-tile 0..15
    const int q0 = qi * 128 + w * 16;      // this wave's 16 q rows
    const int cha = q0 >> 5;               // diagonal 32-chunk
    bf16x8 qf[4];
#pragma unroll
    for (int ec = 0; ec < 4; ec++)
      qf[ec] = *(const bf16x8*)(Q + (long)(q0 + fr) * 128 + ec * 32 + fq * 8);
    float lacc[4];
#pragma unroll
    for (int r = 0; r < 4; r++) lacc[r] = 0.f;
    f32x4 oacc[8];
#pragma unroll
    for (int e = 0; e < 8; e++)
#pragma unroll
      for (int c = 0; c < 4; c++) oacc[e][c] = 0.f;

    const int nst = 2 * qi + 2;
#pragma unroll 1
    for (int st = 0; st < nst; st++) {
      const int k0 = st * 64;
      gl_lds16(gK + (long)k0 * 128, lK);
      gl_lds16(gK + (long)(k0 + 32) * 128, lK + 4096);
      gl_lds16(gV + k0, lV);
      gl_lds16(gV + 64L * 2048 + k0, lV + 4096);
      __syncthreads();
#pragma unroll
      for (int half = 0; half < 2; half++) {
        const int k32 = k0 + half * 32;
        const int ch = k32 >> 5;
        if (ch <= cha) {  // wave-uniform causal skip
          f32x4 sa[2];
#pragma unroll
          for (int ct = 0; ct < 2; ct++)
#pragma unroll
            for (int c = 0; c < 4; c++) sa[ct][c] = 0.f;
#pragma unroll
          for (int ct = 0; ct < 2; ct++) {
#pragma unroll
            for (int ec = 0; ec < 4; ec++) {
              bf16x8 kf = *(const bf16x8*)(&Ks[(half * 32 + ct * 16 + fr) * 128 +
                                               ((ec * 4 + fq) ^ swz) * 8]);
              sa[ct] = __builtin_amdgcn_mfma_f32_16x16x32_bf16(qf[ec], kf, sa[ct], 0, 0, 0);
            }
          }
          if (ch == cha) {  // diagonal: masked
#pragma unroll
            for (int r = 0; r < 4; r++) {
              int qg = q0 + fq * 4 + r;
              float p0 = exp2f(((k32 + fr) <= qg) ? sa[0][r] * sc2 - MFIX : -1e30f);
              float p1 = exp2f(((k32 + 16 + fr) <= qg) ? sa[1][r] * sc2 - MFIX : -1e30f);
              lacc[r] += p0 + p1;
              pw[(fq * 4 + r) * 40 + fr] = (__bf16)p0;
              pw[(fq * 4 + r) * 40 + 16 + fr] = (__bf16)p1;
            }
          } else {  // compare-free fast path
#pragma unroll
            for (int r = 0; r < 4; r++) {
              float p0 = exp2f(__builtin_fmaf(sa[0][r], sc2, -MFIX));
              float p1 = exp2f(__builtin_fmaf(sa[1][r], sc2, -MFIX));
              lacc[r] += p0 + p1;
              pw[(fq * 4 + r) * 40 + fr] = (__bf16)p0;
              pw[(fq * 4 + r) * 40 + 16 + fr] = (__bf16)p1;
            }
          }
          // P: C-layout -> LDS -> A-layout (wave-synchronous)
          bf16x8 pa = *(const bf16x8*)(&pw[fr * 40 + fq * 8]);
#pragma unroll
          for (int e = 0; e < 8; e++) {
            bf16x8 vf = *(const bf16x8*)(&Vs[(e * 16 + fr) * 64 +
                                             ((half * 4 + fq) ^ swz) * 8]);
            oacc[e] = __builtin_amdgcn_mfma_f32_16x16x32_bf16(pa, vf, oacc[e], 0, 0, 0);
          }
        }
      }
      __syncthreads();
    }
    // epilogue: reduce l; /l + rms-norm + store
#pragma unroll
    for (int r = 0; r < 4; r++) {
      float ls = lacc[r];
      ls += __shfl_xor(ls, 1);
      ls += __shfl_xor(ls, 2);
      ls += __shfl_xor(ls, 4);
      ls += __shfl_xor(ls, 8);
      float inv = 1.0f / ls;
      float ssq = 0.f;
#pragma unroll
      for (int e = 0; e < 8; e++) { float v = oacc[e][r] * inv; ssq += v * v; }
      ssq += __shfl_xor(ssq, 1);
      ssq += __shfl_xor(ssq, 2);
      ssq += __shfl_xor(ssq, 4);
      ssq += __shfl_xor(ssq, 8);
      float rsc = rsqrtf(ssq * (1.f / 128.f) + EPSF) * inv;
      long s = q0 + fq * 4 + r;
      __bf16* dst = an + ((long)b * 2048 + s) * 2048 + h * 128;
#pragma unroll
      for (int e = 0; e < 8; e++) dst[e * 16 + fr] = (__bf16)(oacc[e][r] * rsc);
    }
  }
}

// ---------------- launch ----------------
extern "C" void kernel_launch(void* const* d_in, const int* in_sizes, int n_in,
                              void* d_out, int out_size, void* d_ws, size_t ws_size,
                              hipStream_t stream) {
  const float* x = (const float*)d_in[0];
  const float* w_in = (const float*)d_in[1];
  const float* w_out = (const float*)d_in[2];
  float* out = (float*)d_out;
  char* ws = (char*)d_ws;

  __bf16* w_in_n = (__bf16*)(ws);                      // 25165824 B
  __bf16* w_out_n = (__bf16*)(ws + 25165824);          // 8388608 B
  __bf16* xb = (__bf16*)(ws + 33554432);               // 33554432 B (aliased by a_n)
  __bf16* an = xb;
  __bf16* qkv = (__bf16*)(ws + 67108864);              // q,k used (v region unused)
  __bf16* vt = (__bf16*)(ws + 167772160);              // 33554432 B

  norm_w<<<8192, 256, 0, stream>>>(w_in, w_out, w_in_n, w_out_n);
  cast_x<<<8192, 256, 0, stream>>>(x, xb);
  gemm8<1><<<dim3(24, 32), 512, 0, stream>>>(xb, w_in_n, nullptr, qkv, vt, 8192, 6144, 2048);
  attn<<<512, 512, 0, stream>>>(qkv, vt, an);
  gemm8<0><<<dim3(8, 32), 512, 0, stream>>>(an, w_out_n, out, nullptr, nullptr, 8192, 2048, 2048);
}